// Round 1
// baseline (536.914 us; speedup 1.0000x reference)
//
#include <hip/hip_runtime.h>

// Spatial LRN: out = x / (2 + 1e-4 * ssq)^0.75, ssq = 5x5 box sum of x^2 (zero pad 2).
// x: (16, 96, 224, 224) fp32. Memory-bound: ideal ~616 MB HBM traffic.
//
// Layout: flat thread->(job, q) map; each lane owns a float4 column group (4
// consecutive w) of one 56-row strip and slides down rows, keeping 5 horizontal
// row-sums + a 2-deep raw-center ring in registers. All 64 lanes of every wave
// are active (waves may span two jobs; edge masks make the seam correct).
// 16*96 planes * 4 strips = 6144 jobs * 56 lanes = 344064 threads = 1344 blocks.
// Branch-free inner loop: clamped row addresses + 0/1 float masks, unconditional
// loads with 1-iteration prefetch. Read amplification 61/56 (was 32/28).

typedef float f4 __attribute__((ext_vector_type(4)));

#define LRN_H 224
#define LRN_W 224
#define LRN_WQ 56          // float4 groups per row
#define LRN_ROWS 56        // rows per strip
#define LRN_STRIPS 4
#define LRN_PLANE (LRN_H * LRN_W)

// Masked 5-tap horizontal sum of squares for 4 outputs from raw row registers.
// mL/mR zero the out-of-row-edge taps (clamped loads keep addresses in-bounds),
// mV zeroes the whole row when it is outside [0, 224).
__device__ __forceinline__ f4 lrn_hsum(f4 xl, f4 xc, f4 xr,
                                       float mL, float mR, float mV) {
    float a  = xl[2] * xl[2] * mL;
    float b  = xl[3] * xl[3] * mL;
    float c0 = xc[0] * xc[0];
    float c1 = xc[1] * xc[1];
    float c2 = xc[2] * xc[2];
    float c3 = xc[3] * xc[3];
    float d0 = xr[0] * xr[0] * mR;
    float d1 = xr[1] * xr[1] * mR;
    float t = c1 + c2;               // shared by all four windows
    f4 r;
    r[0] = (a + b + c0 + t) * mV;    // cols col-2..col+2
    r[1] = (b + c0 + t + c3) * mV;   // cols col-1..col+3
    r[2] = (c0 + t + c3 + d0) * mV;  // cols col..col+4
    r[3] = (t + c3 + d0 + d1) * mV;  // cols col+1..col+5
    return r;
}

__device__ __forceinline__ void lrn_load(const float* __restrict__ rp,
                                         int offL, int offR,
                                         f4& xl, f4& xc, f4& xr) {
    xc = *(const f4*)rp;
    xl = *(const f4*)(rp + offL);
    xr = *(const f4*)(rp + offR);
}

__global__ __launch_bounds__(256, 6) void LocalResponseNorm_17420387352942_kernel(
        const float* __restrict__ x, float* __restrict__ out) {
    const int gid  = blockIdx.x * 256 + threadIdx.x;
    const int job  = gid / LRN_WQ;          // [0, 6144)
    const int q    = gid - job * LRN_WQ;    // [0, 56) float4 column group
    const int plane = job >> 2;
    const int strip = job & 3;
    const int s0    = strip * LRN_ROWS;

    const float* __restrict__ px = x   + (size_t)plane * LRN_PLANE + (q << 2);
    float* __restrict__       po = out + (size_t)plane * LRN_PLANE + (q << 2);

    const float mL = (q > 0)           ? 1.0f : 0.0f;
    const float mR = (q < LRN_WQ - 1)  ? 1.0f : 0.0f;
    const int offL = (q > 0)           ? -4 : 0;   // clamped: stays in-bounds
    const int offR = (q < LRN_WQ - 1)  ?  4 : 0;

    f4 Al, Ac, Ar;          // in-flight raw row
    f4 r0, r1, r2, r3;      // rowsum ring (rows h-2 .. h+1)
    f4 c0, c1;              // raw center ring (rows h, h+1)

    // Prime: rowsums of rows s0-2 .. s0+1 (clamped+masked at the plane top).
    {
        int row = s0 - 2;
        int rr  = max(row, 0);
        float mV = (row >= 0) ? 1.0f : 0.0f;
        lrn_load(px + rr * LRN_W, offL, offR, Al, Ac, Ar);
        r0 = lrn_hsum(Al, Ac, Ar, mL, mR, mV);
    }
    {
        int row = s0 - 1;
        int rr  = max(row, 0);
        float mV = (row >= 0) ? 1.0f : 0.0f;
        lrn_load(px + rr * LRN_W, offL, offR, Al, Ac, Ar);
        r1 = lrn_hsum(Al, Ac, Ar, mL, mR, mV);
    }
    {
        lrn_load(px + s0 * LRN_W, offL, offR, Al, Ac, Ar);
        r2 = lrn_hsum(Al, Ac, Ar, mL, mR, 1.0f);
        c0 = Ac;
    }
    {
        lrn_load(px + (s0 + 1) * LRN_W, offL, offR, Al, Ac, Ar);
        r3 = lrn_hsum(Al, Ac, Ar, mL, mR, 1.0f);
        c1 = Ac;
    }
    // In-flight: raw row s0+2.
    lrn_load(px + (s0 + 2) * LRN_W, offL, offR, Al, Ac, Ar);

#pragma unroll 2
    for (int i = 0; i < LRN_ROWS; ++i) {
        const int hrow = s0 + i;                   // output row (always valid)

        // Consume A = raw row hrow+2 (loaded one iteration ago).
        const float mV = (hrow + 2 < LRN_H) ? 1.0f : 0.0f;
        f4 r4 = lrn_hsum(Al, Ac, Ar, mL, mR, mV);
        f4 c2 = Ac;                                 // center ring入 (garbage iff mV==0, never used)

        // Prefetch raw row hrow+3 (clamped; independent of everything below).
        {
            int rr = min(hrow + 3, LRN_H - 1);
            lrn_load(px + rr * LRN_W, offL, offR, Al, Ac, Ar);
        }

        f4 s = r0 + r1 + r2 + r3 + r4;

        f4 o;
#pragma unroll
        for (int j = 0; j < 4; ++j) {
            float d  = fmaf(1e-4f, s[j], 2.0f);
            float rs = __builtin_amdgcn_rsqf(d);    // d^-0.5
            o[j] = c0[j] * rs * __builtin_amdgcn_sqrtf(rs);  // * d^-0.25
        }
        __builtin_nontemporal_store(o, (f4*)(po + hrow * LRN_W));

        r0 = r1; r1 = r2; r2 = r3; r3 = r4;
        c0 = c1; c1 = c2;
    }
}

extern "C" void kernel_launch(void* const* d_in, const int* in_sizes, int n_in,
                              void* d_out, int out_size, void* d_ws, size_t ws_size,
                              hipStream_t stream) {
    const float* x = (const float*)d_in[0];
    float* out = (float*)d_out;
    // 6144 jobs * 56 lanes = 344064 threads; 256/block -> 1344 blocks, no tail.
    dim3 block(256, 1, 1);
    dim3 grid(1344, 1, 1);
    LocalResponseNorm_17420387352942_kernel<<<grid, block, 0, stream>>>(x, out);
}

// Round 2
// 516.905 us; speedup vs baseline: 1.0387x; 1.0387x over previous
//
#include <hip/hip_runtime.h>

// Spatial LRN: out = x / (2 + 1e-4 * ssq)^0.75, ssq = 5x5 box sum of x^2 (zero pad 2).
// x: (16, 96, 224, 224) fp32. Latency/MLP-bound per rocprof (2.3 TB/s @ 29% peak,
// VALUBusy 18%, occupancy 50%): fix = more waves x more independent loads in flight.
//
// Layout: block (64,4) = 4 jobs; wave = one job (one 28-row strip of one plane).
// Lane q owns float4 column group q (56 active, 8 lanes guarded; their loads
// duplicate lane 55 and coalesce away). Per row: ONE float4 load per lane;
// horizontal neighbor taps come from adjacent lanes via __shfl (cuts read
// requests 3x vs xl/xc/xr loads and saves ~16 VGPR). Raw-row prefetch ring of
// depth 3 keeps 48 B/lane of independent loads in flight. Rowsum ring (5 rows)
// + raw-center ring (2 rows) slide down the strip. Full unroll => all ring
// indices compile-time (registers, not scratch).
// 16*96 planes * 8 strips = 12288 jobs -> 3072 blocks -> 48 waves/CU supplied.

typedef float f4 __attribute__((ext_vector_type(4)));

#define LRN_H 224
#define LRN_W 224
#define LRN_WQ 56          // float4 groups per row
#define LRN_ROWS 28        // rows per strip
#define LRN_PLANE (LRN_H * LRN_W)

__device__ __forceinline__ f4 lrn_ld(const float* __restrict__ p) {
    return *(const f4*)p;
}

// Masked 5-tap horizontal sum of squares for 4 outputs; neighbor taps via
// cross-lane shuffle of the squared values. Seam taps use cndmask (ternary)
// so garbage from guarded/edge lanes can never inject NaN.
__device__ __forceinline__ f4 lrn_rowsum_sh(f4 xc, bool okL, bool okR, float mV) {
    f4 sq = xc * xc;
    float a  = __shfl_up(sq[2], 1);    // lane q-1: col 4q-2
    float b  = __shfl_up(sq[3], 1);    // lane q-1: col 4q-1
    float d0 = __shfl_down(sq[0], 1);  // lane q+1: col 4q+4
    float d1 = __shfl_down(sq[1], 1);  // lane q+1: col 4q+5
    a  = okL ? a  : 0.0f;
    b  = okL ? b  : 0.0f;
    d0 = okR ? d0 : 0.0f;
    d1 = okR ? d1 : 0.0f;
    float t = sq[1] + sq[2];           // shared by all four windows
    f4 r;
    r[0] = (a + b + sq[0] + t) * mV;   // cols 4q-2 .. 4q+2
    r[1] = (b + sq[0] + t + sq[3]) * mV;
    r[2] = (sq[0] + t + sq[3] + d0) * mV;
    r[3] = (t + sq[3] + d0 + d1) * mV;
    return r;
}

__global__ __launch_bounds__(256) void LocalResponseNorm_17420387352942_kernel(
        const float* __restrict__ x, float* __restrict__ out) {
    const int q   = threadIdx.x;                   // 0..63
    const int qe  = min(q, LRN_WQ - 1);            // guarded lanes mirror lane 55
    const int job = blockIdx.x * 4 + threadIdx.y;  // plane*8 + strip
    const int plane = job >> 3;
    const int strip = job & 7;
    const int s0    = strip * LRN_ROWS;

    const float* __restrict__ px = x   + (size_t)plane * LRN_PLANE + (qe << 2);
    float* __restrict__       po = out + (size_t)plane * LRN_PLANE + (qe << 2);

    const bool okL = (qe > 0);
    const bool okR = (qe < LRN_WQ - 1);
    const bool wr  = (q < LRN_WQ);

    // ---- Prologue: rowsums of rows s0-2 .. s0+1, raw-center ring rows s0, s0+1.
    f4 x0 = lrn_ld(px + max(s0 - 2, 0) * LRN_W);
    f4 x1 = lrn_ld(px + max(s0 - 1, 0) * LRN_W);
    f4 x2 = lrn_ld(px + s0 * LRN_W);
    f4 x3 = lrn_ld(px + (s0 + 1) * LRN_W);
    f4 r0 = lrn_rowsum_sh(x0, okL, okR, (s0 - 2 >= 0) ? 1.0f : 0.0f);
    f4 r1 = lrn_rowsum_sh(x1, okL, okR, (s0 - 1 >= 0) ? 1.0f : 0.0f);
    f4 r2 = lrn_rowsum_sh(x2, okL, okR, 1.0f);
    f4 r3 = lrn_rowsum_sh(x3, okL, okR, 1.0f);
    f4 c0 = x2, c1 = x3;

    // In-flight raw-row ring, depth 3: rows s0+2, s0+3, s0+4 (clamped; masked on use).
    f4 A0 = lrn_ld(px + min(s0 + 2, LRN_H - 1) * LRN_W);
    f4 A1 = lrn_ld(px + min(s0 + 3, LRN_H - 1) * LRN_W);
    f4 A2 = lrn_ld(px + min(s0 + 4, LRN_H - 1) * LRN_W);

#pragma unroll
    for (int i = 0; i < LRN_ROWS; ++i) {
        const int h = s0 + i;                       // output row (always valid)

        // Consume raw row h+2 (issued 3 iterations ago).
        f4 cur = (i % 3 == 0) ? A0 : (i % 3 == 1) ? A1 : A2;
        const float mV = (h + 2 < LRN_H) ? 1.0f : 0.0f;
        f4 r4 = lrn_rowsum_sh(cur, okL, okR, mV);

        // Refill the just-consumed slot with raw row h+5 (clamped, independent).
        {
            f4 nxt = lrn_ld(px + min(h + 5, LRN_H - 1) * LRN_W);
            if (i % 3 == 0) A0 = nxt; else if (i % 3 == 1) A1 = nxt; else A2 = nxt;
        }

        f4 s = r0 + r1 + r2 + r3 + r4;

        f4 o;
#pragma unroll
        for (int j = 0; j < 4; ++j) {
            float d  = fmaf(1e-4f, s[j], 2.0f);
            float rs = __builtin_amdgcn_rsqf(d);             // d^-0.5
            o[j] = c0[j] * rs * __builtin_amdgcn_sqrtf(rs);  // * d^-0.25
        }
        if (wr) __builtin_nontemporal_store(o, (f4*)(po + h * LRN_W));

        r0 = r1; r1 = r2; r2 = r3; r3 = r4;
        c0 = c1; c1 = cur;
    }
}

extern "C" void kernel_launch(void* const* d_in, const int* in_sizes, int n_in,
                              void* d_out, int out_size, void* d_ws, size_t ws_size,
                              hipStream_t stream) {
    const float* x = (const float*)d_in[0];
    float* out = (float*)d_out;
    // 12288 jobs, 4 jobs per block -> 3072 blocks of (64,4).
    dim3 block(64, 4, 1);
    dim3 grid(3072, 1, 1);
    LocalResponseNorm_17420387352942_kernel<<<grid, block, 0, stream>>>(x, out);
}

// Round 3
// 496.027 us; speedup vs baseline: 1.0824x; 1.0421x over previous
//
#include <hip/hip_runtime.h>

// Spatial LRN: out = x / (2 + 1e-4 * ssq)^0.75, ssq = 5x5 box sum of x^2 (zero pad 2).
// x: (16, 96, 224, 224) fp32.
//
// Round-3 structure: burst-independent register jobs. Previous rounds slid a
// rowsum ring down a strip -> loop-carried dependence chain (waitcnt-serialized,
// 2.3-2.6 TB/s). Here one wave computes an 8-row x 224-col output slab as
// STRAIGHT-LINE code: 36 independent loads (12 input rows x {xl,xc,xr},
// clamped + masked) issue up front, fold into 12 rowsums as they land, then
// 8 output rows come purely from registers. No loop-carried state, no
// shuffles, no barriers -> deep MLP per wave, no per-row serialization.
// xl/xr hit the neighbor lane's cache lines (L1); halo rows (4/12) are
// L2-shared with vertical-neighbor jobs.
//
// Lane q owns float4 column group q (56 active, 8 lanes mirror lane 55 and
// never store). Jobs = 16*96 planes * 28 row-slabs = 43008 waves -> 10752
// blocks of 256 (4 jobs/block).

typedef float f4 __attribute__((ext_vector_type(4)));

#define LRN_H 224
#define LRN_W 224
#define LRN_WQ 56          // float4 groups per row
#define LRN_R 8            // output rows per job
#define LRN_JOBS_PER_PLANE (LRN_H / LRN_R)   // 28
#define LRN_PLANE (LRN_H * LRN_W)

__device__ __forceinline__ f4 lrn_ld(const float* __restrict__ p) {
    return *(const f4*)p;
}

// 5-tap horizontal sum of squares for 4 outputs. mL/mR zero the row-edge taps
// (clamped addresses keep loads in-bounds), mV zeroes the whole row.
__device__ __forceinline__ f4 lrn_hsum(f4 xl, f4 xc, f4 xr,
                                       float mL, float mR, float mV) {
    float a  = xl[2] * xl[2] * mL;
    float b  = xl[3] * xl[3] * mL;
    float c0 = xc[0] * xc[0];
    float c1 = xc[1] * xc[1];
    float c2 = xc[2] * xc[2];
    float c3 = xc[3] * xc[3];
    float d0 = xr[0] * xr[0] * mR;
    float d1 = xr[1] * xr[1] * mR;
    float t = c1 + c2;               // shared by all four windows
    f4 r;
    r[0] = (a + b + c0 + t) * mV;    // cols 4q-2 .. 4q+2
    r[1] = (b + c0 + t + c3) * mV;
    r[2] = (c0 + t + c3 + d0) * mV;
    r[3] = (t + c3 + d0 + d1) * mV;
    return r;
}

__global__ __launch_bounds__(256, 4) void LocalResponseNorm_17420387352942_kernel(
        const float* __restrict__ x, float* __restrict__ out) {
    const int q    = threadIdx.x & 63;
    const int wave = threadIdx.x >> 6;
    const int job  = blockIdx.x * 4 + wave;        // [0, 43008)
    const int plane = job / LRN_JOBS_PER_PLANE;
    const int slab  = job - plane * LRN_JOBS_PER_PLANE;
    const int h0    = slab * LRN_R;                // first output row

    const int qe = min(q, LRN_WQ - 1);             // guard lanes mirror lane 55
    const float* __restrict__ px = x   + (size_t)plane * LRN_PLANE + (qe << 2);
    float* __restrict__       po = out + (size_t)plane * LRN_PLANE + (qe << 2);

    const float mL = (qe > 0)          ? 1.0f : 0.0f;
    const float mR = (qe < LRN_WQ - 1) ? 1.0f : 0.0f;
    const int offL = (qe > 0)          ? -4 : 0;
    const int offR = (qe < LRN_WQ - 1) ?  4 : 0;
    const bool wr  = (q < LRN_WQ);

    // 12 input rows h0-2 .. h0+9 -> 12 rowsums + 8 raw centers, all registers.
    f4 rs[LRN_R + 4];
    f4 cen[LRN_R];

#pragma unroll
    for (int r = 0; r < LRN_R + 4; ++r) {
        const int row = h0 + r - 2;
        // Rows r=2..9 are output rows h0..h0+7: always in-bounds (compile-time).
        float mV = 1.0f;
        int rc = row;
        if (r < 2)      { mV = (row >= 0)     ? 1.0f : 0.0f; rc = max(row, 0); }
        else if (r > 9) { mV = (row < LRN_H)  ? 1.0f : 0.0f; rc = min(row, LRN_H - 1); }
        const float* rp = px + rc * LRN_W;
        f4 xc = lrn_ld(rp);
        f4 xl = lrn_ld(rp + offL);
        f4 xr = lrn_ld(rp + offR);
        rs[r] = lrn_hsum(xl, xc, xr, mL, mR, mV);
        if (r >= 2 && r < 2 + LRN_R) cen[r - 2] = xc;
    }

#pragma unroll
    for (int i = 0; i < LRN_R; ++i) {
        f4 s = rs[i] + rs[i + 1] + rs[i + 2] + rs[i + 3] + rs[i + 4];
        f4 o;
#pragma unroll
        for (int j = 0; j < 4; ++j) {
            float d  = fmaf(1e-4f, s[j], 2.0f);
            float rsq = __builtin_amdgcn_rsqf(d);              // d^-0.5
            o[j] = cen[i][j] * rsq * __builtin_amdgcn_sqrtf(rsq); // * d^-0.25
        }
        if (wr) __builtin_nontemporal_store(o, (f4*)(po + (h0 + i) * LRN_W));
    }
}

extern "C" void kernel_launch(void* const* d_in, const int* in_sizes, int n_in,
                              void* d_out, int out_size, void* d_ws, size_t ws_size,
                              hipStream_t stream) {
    const float* x = (const float*)d_in[0];
    float* out = (float*)d_out;
    // 16*96 planes * 28 slabs = 43008 jobs; 4 jobs (waves) per block.
    dim3 block(256, 1, 1);
    dim3 grid(43008 / 4, 1, 1);
    LocalResponseNorm_17420387352942_kernel<<<grid, block, 0, stream>>>(x, out);
}